// Round 4
// baseline (83.265 us; speedup 1.0000x reference)
//
#include <hip/hip_runtime.h>

typedef __attribute__((ext_vector_type(8))) short short8;
typedef __attribute__((ext_vector_type(4))) float f32x4;

// round-to-nearest-even f32 -> bf16 bits
__device__ __forceinline__ unsigned short f2b(float f) {
  unsigned int u = __float_as_uint(f);
  unsigned int r = (u + 0x7FFFu + ((u >> 16) & 1u)) >> 16;
  return (unsigned short)r;
}

// Harness stores the reference complex64 output through its float32 path:
// d_out is float*, out_size = 8192*4096, holding Re(out) only.
// Re(out)[b, i*64+k] = sum_j cos(phase[j][i])*hr[b,j*64+k] - sin(phase[j][i])*hi[b,j*64+k]
//
// Block: 512 threads = 8 waves, 4 batches. Wave w: batch = w>>1, i-half = w&1 (M=32).
// LDS: per (batch, re/im): [k=64 rows][j=64 bf16] rows of 128B, XOR-swizzled 16B chunks.
// psi fragments (cos, -sin) computed in-register per wave from phase (16KB, cache-resident).
__global__ __launch_bounds__(512, 4) void tnn_kernel(
    const float* __restrict__ phase,
    const float* __restrict__ hr, const float* __restrict__ hi,
    float* __restrict__ out) {
  __shared__ alignas(16) char lds[65536];
  const int t = threadIdx.x;
  const int lane = t & 63;
  const int w8 = t >> 6;           // wave id 0..7
  const int b0 = blockIdx.x * 4;

  const int bb = w8 >> 1;          // which of 4 batches this wave computes
  const int ibase = (w8 & 1) * 32; // which i-half (M=32)

  // ---- stage X into LDS (transpose j into contiguous runs, f32->bf16) ----
  // wave w8 stages j in [w8*8, w8*8+8) for all k; thread: k = lane.
  {
    const int row = lane;  // k (output column index)
    const int swz = (w8 * 16) ^ ((row & 7) << 4);
    const int wbyte = row * 128 + swz;
#pragma unroll
    for (int b = 0; b < 4; ++b) {
      const float* s0 = hr + (size_t)(b0 + b) * 4096 + (size_t)(w8 * 8) * 64 + lane;
      const float* s1 = hi + (size_t)(b0 + b) * 4096 + (size_t)(w8 * 8) * 64 + lane;
      float v0[8], v1[8];
#pragma unroll
      for (int q = 0; q < 8; ++q) v0[q] = s0[(size_t)q * 64];
#pragma unroll
      for (int q = 0; q < 8; ++q) v1[q] = s1[(size_t)q * 64];
      uint4 p0, p1;
      p0.x = f2b(v0[0]) | ((unsigned)f2b(v0[1]) << 16);
      p0.y = f2b(v0[2]) | ((unsigned)f2b(v0[3]) << 16);
      p0.z = f2b(v0[4]) | ((unsigned)f2b(v0[5]) << 16);
      p0.w = f2b(v0[6]) | ((unsigned)f2b(v0[7]) << 16);
      p1.x = f2b(v1[0]) | ((unsigned)f2b(v1[1]) << 16);
      p1.y = f2b(v1[2]) | ((unsigned)f2b(v1[3]) << 16);
      p1.z = f2b(v1[4]) | ((unsigned)f2b(v1[5]) << 16);
      p1.w = f2b(v1[6]) | ((unsigned)f2b(v1[7]) << 16);
      *reinterpret_cast<uint4*>(lds + (b * 2 + 0) * 8192 + wbyte) = p0;
      *reinterpret_cast<uint4*>(lds + (b * 2 + 1) * 8192 + wbyte) = p1;
    }
  }

  // ---- psi A-fragments in-register: Are = cos(phase[j][i]), Ans = -sin(phase[j][i]) ----
  // A-frag lane mapping (16x16x32): row m = lane&15, k = (lane>>4)*8 + q.
  short8 Are[2][2], Ans[2][2];
#pragma unroll
  for (int it = 0; it < 2; ++it) {
#pragma unroll
    for (int ks = 0; ks < 2; ++ks) {
      const int i = ibase + it * 16 + (lane & 15);
      const int j0 = ks * 32 + (lane >> 4) * 8;
#pragma unroll
      for (int q = 0; q < 8; ++q) {
        float p = phase[(j0 + q) * 64 + i];
        float s, c;
        __sincosf(p, &s, &c);
        Are[it][ks][q] = (short)f2b(c);
        Ans[it][ks][q] = (short)f2b(-s);
      }
    }
  }

  __syncthreads();

  // ---- MFMA compute (real part only) ----
  f32x4 acc[2][4] = {};
  const char* Xre = lds + (bb * 2 + 0) * 8192;
  const char* Xim = lds + (bb * 2 + 1) * 8192;

#pragma unroll
  for (int kt = 0; kt < 4; ++kt) {
    const int row = kt * 16 + (lane & 15);
#pragma unroll
    for (int ks = 0; ks < 2; ++ks) {
      const int cbyte = ks * 64 + (lane >> 4) * 16;  // (ks*32 + g*8) elems * 2B
      const int byte = row * 128 + (cbyte ^ ((row & 7) << 4));
      uint4 xr4 = *reinterpret_cast<const uint4*>(Xre + byte);
      uint4 xi4 = *reinterpret_cast<const uint4*>(Xim + byte);
      short8 xr = __builtin_bit_cast(short8, xr4);
      short8 xi = __builtin_bit_cast(short8, xi4);
#pragma unroll
      for (int it = 0; it < 2; ++it) {
        acc[it][kt] = __builtin_amdgcn_mfma_f32_16x16x32_bf16(Are[it][ks], xr, acc[it][kt], 0, 0, 0);
        acc[it][kt] = __builtin_amdgcn_mfma_f32_16x16x32_bf16(Ans[it][ks], xi, acc[it][kt], 0, 0, 0);
      }
    }
  }

  // ---- epilogue: scalar f32 stores (real part), in-bounds ----
  // C/D lane mapping (16x16x32): col = lane&15, row = (lane>>4)*4 + r.
  const size_t obase = (size_t)(b0 + bb) * 4096;
#pragma unroll
  for (int it = 0; it < 2; ++it) {
#pragma unroll
    for (int kt = 0; kt < 4; ++kt) {
#pragma unroll
      for (int r = 0; r < 4; ++r) {
        int i = ibase + it * 16 + (lane >> 4) * 4 + r;
        int kc = kt * 16 + (lane & 15);
        out[obase + (size_t)i * 64 + kc] = acc[it][kt][r];
      }
    }
  }
}

extern "C" void kernel_launch(void* const* d_in, const int* in_sizes, int n_in,
                              void* d_out, int out_size, void* d_ws, size_t ws_size,
                              hipStream_t stream) {
  const float* phase = (const float*)d_in[0];
  const float* hr = (const float*)d_in[1];
  const float* hi = (const float*)d_in[2];
  float* out = (float*)d_out;

  tnn_kernel<<<2048, 512, 0, stream>>>(phase, hr, hi, out);
}

// Round 5
// 76.582 us; speedup vs baseline: 1.0873x; 1.0873x over previous
//
#include <hip/hip_runtime.h>

typedef __attribute__((ext_vector_type(8))) short short8;
typedef __attribute__((ext_vector_type(4))) float f32x4;

// round-to-nearest-even f32 -> bf16 bits
__device__ __forceinline__ unsigned short f2b(float f) {
  unsigned int u = __float_as_uint(f);
  unsigned int r = (u + 0x7FFFu + ((u >> 16) & 1u)) >> 16;
  return (unsigned short)r;
}

// d_out is float*, out_size = 8192*4096, holding Re(out) only:
// Re(out)[b, i*64+k] = sum_j cos(phase[j][i])*hr[b,j*64+k] - sin(phase[j][i])*hi[b,j*64+k]
//
// Block: 512 threads = 8 waves, 2 batches (32KB LDS -> 4 blocks/CU, wave-slot bound).
// Wave w: batch = w>>2, i-quarter = w&3 (M=16).
// LDS: per (batch, re/im): [k=64 rows][j=64 bf16] rows of 128B, XOR-swizzled 16B chunks.
// psi fragments (cos, -sin) computed in-register per wave from phase (16KB, cache-resident).
__global__ __launch_bounds__(512, 4) void tnn_kernel(
    const float* __restrict__ phase,
    const float* __restrict__ hr, const float* __restrict__ hi,
    float* __restrict__ out) {
  __shared__ alignas(16) char lds[32768];
  const int t = threadIdx.x;
  const int lane = t & 63;
  const int w8 = t >> 6;            // wave id 0..7
  const int b0 = blockIdx.x * 2;

  const int bb = w8 >> 2;           // which of 2 batches this wave computes
  const int ibase = (w8 & 3) * 16;  // which i-quarter (M=16)

  // ---- stage X into LDS (transpose j into contiguous runs, f32->bf16) ----
  // wave w8 stages j in [w8*8, w8*8+8) for both batches; thread: k = lane.
  {
    const int row = lane;  // k (output column index)
    const int swz = (w8 * 16) ^ ((row & 7) << 4);
    const int wbyte = row * 128 + swz;
#pragma unroll
    for (int b = 0; b < 2; ++b) {
      const float* s0 = hr + (size_t)(b0 + b) * 4096 + (size_t)(w8 * 8) * 64 + lane;
      const float* s1 = hi + (size_t)(b0 + b) * 4096 + (size_t)(w8 * 8) * 64 + lane;
      float v0[8], v1[8];
#pragma unroll
      for (int q = 0; q < 8; ++q) v0[q] = s0[(size_t)q * 64];
#pragma unroll
      for (int q = 0; q < 8; ++q) v1[q] = s1[(size_t)q * 64];
      uint4 p0, p1;
      p0.x = f2b(v0[0]) | ((unsigned)f2b(v0[1]) << 16);
      p0.y = f2b(v0[2]) | ((unsigned)f2b(v0[3]) << 16);
      p0.z = f2b(v0[4]) | ((unsigned)f2b(v0[5]) << 16);
      p0.w = f2b(v0[6]) | ((unsigned)f2b(v0[7]) << 16);
      p1.x = f2b(v1[0]) | ((unsigned)f2b(v1[1]) << 16);
      p1.y = f2b(v1[2]) | ((unsigned)f2b(v1[3]) << 16);
      p1.z = f2b(v1[4]) | ((unsigned)f2b(v1[5]) << 16);
      p1.w = f2b(v1[6]) | ((unsigned)f2b(v1[7]) << 16);
      *reinterpret_cast<uint4*>(lds + (b * 2 + 0) * 8192 + wbyte) = p0;
      *reinterpret_cast<uint4*>(lds + (b * 2 + 1) * 8192 + wbyte) = p1;
    }
  }

  // ---- psi A-fragments in-register: Are = cos(phase[j][i]), Ans = -sin(phase[j][i]) ----
  // A-frag lane mapping (16x16x32): row m = lane&15, k = (lane>>4)*8 + q.
  short8 Are[2], Ans[2];
#pragma unroll
  for (int ks = 0; ks < 2; ++ks) {
    const int i = ibase + (lane & 15);
    const int j0 = ks * 32 + (lane >> 4) * 8;
#pragma unroll
    for (int q = 0; q < 8; ++q) {
      float p = phase[(j0 + q) * 64 + i];
      float s, c;
      __sincosf(p, &s, &c);
      Are[ks][q] = (short)f2b(c);
      Ans[ks][q] = (short)f2b(-s);
    }
  }

  __syncthreads();

  // ---- MFMA compute (real part only) ----
  f32x4 acc[4] = {};
  const char* Xre = lds + (bb * 2 + 0) * 8192;
  const char* Xim = lds + (bb * 2 + 1) * 8192;

#pragma unroll
  for (int kt = 0; kt < 4; ++kt) {
    const int row = kt * 16 + (lane & 15);
#pragma unroll
    for (int ks = 0; ks < 2; ++ks) {
      const int cbyte = ks * 64 + (lane >> 4) * 16;  // (ks*32 + g*8) elems * 2B
      const int byte = row * 128 + (cbyte ^ ((row & 7) << 4));
      uint4 xr4 = *reinterpret_cast<const uint4*>(Xre + byte);
      uint4 xi4 = *reinterpret_cast<const uint4*>(Xim + byte);
      short8 xr = __builtin_bit_cast(short8, xr4);
      short8 xi = __builtin_bit_cast(short8, xi4);
      acc[kt] = __builtin_amdgcn_mfma_f32_16x16x32_bf16(Are[ks], xr, acc[kt], 0, 0, 0);
      acc[kt] = __builtin_amdgcn_mfma_f32_16x16x32_bf16(Ans[ks], xi, acc[kt], 0, 0, 0);
    }
  }

  // ---- epilogue: scalar f32 stores (real part), in-bounds ----
  // C/D lane mapping (16x16x32): col = lane&15, row = (lane>>4)*4 + r.
  const size_t obase = (size_t)(b0 + bb) * 4096;
#pragma unroll
  for (int kt = 0; kt < 4; ++kt) {
#pragma unroll
    for (int r = 0; r < 4; ++r) {
      int i = ibase + (lane >> 4) * 4 + r;
      int kc = kt * 16 + (lane & 15);
      out[obase + (size_t)i * 64 + kc] = acc[kt][r];
    }
  }
}

extern "C" void kernel_launch(void* const* d_in, const int* in_sizes, int n_in,
                              void* d_out, int out_size, void* d_ws, size_t ws_size,
                              hipStream_t stream) {
  const float* phase = (const float*)d_in[0];
  const float* hr = (const float*)d_in[1];
  const float* hi = (const float*)d_in[2];
  float* out = (float*)d_out;

  tnn_kernel<<<4096, 512, 0, stream>>>(phase, hr, hi, out);
}